// Round 3
// baseline (477.450 us; speedup 1.0000x reference)
//
#include <hip/hip_runtime.h>
#include <cstdint>
#include <cstddef>

#define NEG_SLOPE 0.2f

typedef short bf16x8 __attribute__((ext_vector_type(8)));
typedef float f32x4 __attribute__((ext_vector_type(4)));

// ---------- bf16 <-> f32 helpers (bit-level, RNE) ----------
__device__ __forceinline__ unsigned short f2bf(float f) {
  unsigned u = __float_as_uint(f);
  u = u + 0x7FFFu + ((u >> 16) & 1u);
  return (unsigned short)(u >> 16);
}
__device__ __forceinline__ float bf2f(unsigned short b) {
  return __uint_as_float((unsigned)b << 16);
}

// ---------- casts ----------
__global__ void cast4(const float* __restrict__ in, unsigned short* __restrict__ outp,
                      int n4) {
  int i = blockIdx.x * blockDim.x + threadIdx.x;
  if (i >= n4) return;
  float4 v = ((const float4*)in)[i];
  ushort4 o;
  o.x = f2bf(v.x); o.y = f2bf(v.y); o.z = f2bf(v.z); o.w = f2bf(v.w);
  ((ushort4*)outp)[i] = o;
}

// W[K][Nc] fp32 -> Wt[Nc][K] bf16
__global__ void cast_t(const float* __restrict__ W, unsigned short* __restrict__ Wt,
                       int K, int Nc) {
  int i = blockIdx.x * blockDim.x + threadIdx.x;
  if (i >= K * Nc) return;
  int k = i / Nc, nn = i % Nc;
  Wt[(size_t)nn * K + k] = f2bf(W[i]);
}

// ---------- AsAdT[16][128]: o<8 -> src-att dot vec for head o; o>=8 -> dst-att ----------
// AsAdT[o][k] = sum_c W1[k][h*64+c] * att[h][c],  h = o&7
__global__ void prep_asad(const float* __restrict__ W1, const float* __restrict__ att_s,
                          const float* __restrict__ att_d, unsigned short* __restrict__ AsAdT) {
  int i = blockIdx.x * blockDim.x + threadIdx.x;
  if (i >= 16 * 128) return;
  int o = i >> 7, k = i & 127, h = o & 7;
  const float* att = (o < 8) ? att_s : att_d;
  float s = 0.f;
  for (int c = 0; c < 64; c++) s += W1[(size_t)k * 512 + h * 64 + c] * att[h * 64 + c];
  AsAdT[i] = f2bf(s);
}

// ---------- WbT[64][1024]: WbT[o][h*128+c] = W1[c][h*64+o] ----------
__global__ void prep_wbig(const float* __restrict__ W1, unsigned short* __restrict__ WbT) {
  int i = blockIdx.x * blockDim.x + threadIdx.x;
  if (i >= 64 * 1024) return;
  int o = i >> 10, k = i & 1023, h = k >> 7, c = k & 127;
  WbT[i] = f2bf(W1[(size_t)c * 512 + h * 64 + o]);
}

// ---------- asd[node][16] = xb @ AsAdT^T via MFMA ----------
__global__ __launch_bounds__(256) void dots_mfma(
    const unsigned short* __restrict__ xb, const unsigned short* __restrict__ AsAdT,
    float* __restrict__ asd, int M) {
  int wave = threadIdx.x >> 6, lane = threadIdx.x & 63;
  int q = lane >> 4, t = lane & 15;
  int row0 = blockIdx.x * 64 + wave * 16;
  int arow = row0 + t; if (arow > M - 1) arow = M - 1;
  const bf16x8* aptr = (const bf16x8*)(xb + (size_t)arow * 128);
  const bf16x8* bptr = (const bf16x8*)(AsAdT + t * 128);
  f32x4 acc = (f32x4){0.f, 0.f, 0.f, 0.f};
  #pragma unroll
  for (int s = 0; s < 4; s++)
    acc = __builtin_amdgcn_mfma_f32_16x16x32_bf16(aptr[s * 4 + q], bptr[s * 4 + q],
                                                  acc, 0, 0, 0);
  #pragma unroll
  for (int r = 0; r < 4; r++) {
    int row = row0 + q * 4 + r;
    if (row < M) asd[row * 16 + t] = acc[r];
  }
}

// ---------- fused GEMM + attention dots (layer 2) ----------
template <int KS, int H>
__global__ __launch_bounds__(256) void gemm_attn(
    const unsigned short* __restrict__ Ab, const unsigned short* __restrict__ Wt,
    const float* __restrict__ atts, const float* __restrict__ attd,
    unsigned short* __restrict__ Hout, float* __restrict__ as_out,
    float* __restrict__ ad_out, int M) {
  const int K = KS * 32;
  int wave = threadIdx.x >> 6, lane = threadIdx.x & 63;
  int q = lane >> 4, t = lane & 15;
  int hd = blockIdx.y;
  int row0 = blockIdx.x * 64 + wave * 16;

  int arow = row0 + t; if (arow > M - 1) arow = M - 1;
  const bf16x8* aptr = (const bf16x8*)(Ab + (size_t)arow * K);
  bf16x8 afr[KS];
  #pragma unroll
  for (int s = 0; s < KS; s++) afr[s] = aptr[s * 4 + q];

  f32x4 acc[4];
  #pragma unroll
  for (int c = 0; c < 4; c++) acc[c] = (f32x4){0.f, 0.f, 0.f, 0.f};
  #pragma unroll
  for (int c = 0; c < 4; c++) {
    const bf16x8* bptr = (const bf16x8*)(Wt + (size_t)(hd * 64 + c * 16 + t) * K);
    #pragma unroll
    for (int s = 0; s < KS; s++) {
      acc[c] = __builtin_amdgcn_mfma_f32_16x16x32_bf16(afr[s], bptr[s * 4 + q],
                                                       acc[c], 0, 0, 0);
    }
  }

  float ps[4] = {0, 0, 0, 0}, pd[4] = {0, 0, 0, 0};
  #pragma unroll
  for (int c = 0; c < 4; c++) {
    int col = c * 16 + t;
    float ws = atts[hd * 64 + col], wd = attd[hd * 64 + col];
    #pragma unroll
    for (int r = 0; r < 4; r++) {
      float v = acc[c][r];
      int row = row0 + q * 4 + r;
      if (row < M) Hout[(size_t)row * (H * 64) + hd * 64 + col] = f2bf(v);
      ps[r] += v * ws;
      pd[r] += v * wd;
    }
  }
  #pragma unroll
  for (int r = 0; r < 4; r++) {
    float s = ps[r], d = pd[r];
    #pragma unroll
    for (int off = 1; off < 16; off <<= 1) {
      s += __shfl_xor(s, off, 64);
      d += __shfl_xor(d, off, 64);
    }
    int row = row0 + q * 4 + r;
    if (t == 0 && row < M) {
      as_out[row * H + hd] = s;
      ad_out[row * H + hd] = d;
    }
  }
}

// ---------- CSR build ----------
__global__ void count_dst(const int* __restrict__ ei, int* __restrict__ counts,
                          int E, int ET) {
  int i = blockIdx.x * blockDim.x + threadIdx.x;
  if (i >= ET) return;
  int dst = (i < E) ? ei[E + i] : (i - E);
  atomicAdd(&counts[dst], 1);
}

__global__ __launch_bounds__(1024) void scan_offsets(
    const int* __restrict__ counts, int* __restrict__ offsets, int n) {
  __shared__ int sums[1024];
  int t = threadIdx.x;
  int chunk = (n + 1023) >> 10;
  int start = t * chunk;
  int end = min(start + chunk, n);
  int s = 0;
  for (int i = start; i < end; i++) s += counts[i];
  sums[t] = s;
  __syncthreads();
  for (int off = 1; off < 1024; off <<= 1) {
    int v = (t >= off) ? sums[t - off] : 0;
    __syncthreads();
    sums[t] += v;
    __syncthreads();
  }
  int run = sums[t] - s;
  for (int i = start; i < end; i++) { offsets[i] = run; run += counts[i]; }
  if (t == 1023) offsets[n] = sums[1023];
}

__global__ void fill_srcs(const int* __restrict__ ei, const int* __restrict__ offsets,
                          int* __restrict__ cursor, int* __restrict__ srcs,
                          int* __restrict__ dstof, int E, int ET) {
  int i = blockIdx.x * blockDim.x + threadIdx.x;
  if (i >= ET) return;
  int src, dst;
  if (i < E) { src = ei[i]; dst = ei[E + i]; } else { src = dst = i - E; }
  int pos = atomicAdd(&cursor[dst], 1);
  int slot = offsets[dst] + pos;
  srcs[slot] = src;
  dstof[slot] = dst;
}

// ---------- per-(csr-edge, head) softmax numerators, CSR order ----------
__global__ void weights1(const int* __restrict__ srcs, const int* __restrict__ dstof,
                         const float* __restrict__ asd, float* __restrict__ wbuf,
                         int ET) {
  int i = blockIdx.x * blockDim.x + threadIdx.x;
  if (i >= ET * 8) return;
  int j = i >> 3, h = i & 7;
  int src = srcs[j], dst = dstof[j];
  float v = asd[src * 16 + h] + asd[dst * 16 + 8 + h];
  v = (v > 0.f) ? v : NEG_SLOPE * v;
  wbuf[i] = __expf(v);
}

__global__ void weights2(const int* __restrict__ srcs, const int* __restrict__ dstof,
                         const float* __restrict__ as2, const float* __restrict__ ad2,
                         float* __restrict__ wbuf, int ET) {
  int j = blockIdx.x * blockDim.x + threadIdx.x;
  if (j >= ET) return;
  float v = as2[srcs[j]] + ad2[dstof[j]];
  v = (v > 0.f) ? v : NEG_SLOPE * v;
  wbuf[j] = __expf(v);
}

// ---------- layer-1 aggregation over x: block per dst; wave w -> heads 2w,2w+1 ----------
__global__ __launch_bounds__(256) void aggregate_x(
    const int* __restrict__ offsets, const int* __restrict__ srcs,
    const float* __restrict__ wbuf, const unsigned short* __restrict__ xb,
    unsigned short* __restrict__ Xagg) {
  int node = blockIdx.x;
  int wave = threadIdx.x >> 6, lane = threadIdx.x & 63;
  int h0 = wave * 2, h1 = h0 + 1;
  int c = lane * 2;
  int beg = offsets[node], end = offsets[node + 1];
  float a00 = 0.f, a01 = 0.f, a10 = 0.f, a11 = 0.f, w0s = 0.f, w1s = 0.f;
  for (int j = beg; j < end; j++) {
    int src = srcs[j];
    float w0 = wbuf[j * 8 + h0];
    float w1 = wbuf[j * 8 + h1];
    unsigned xv = *(const unsigned*)&xb[(size_t)src * 128 + c];
    float x0 = bf2f((unsigned short)(xv & 0xFFFFu));
    float x1 = bf2f((unsigned short)(xv >> 16));
    a00 += w0 * x0; a01 += w0 * x1;
    a10 += w1 * x0; a11 += w1 * x1;
    w0s += w0; w1s += w1;
  }
  float i0 = 0.125f / w0s, i1 = 0.125f / w1s;  // fold head-mean /8
  unsigned o0 = (unsigned)f2bf(a00 * i0) | ((unsigned)f2bf(a01 * i0) << 16);
  unsigned o1 = (unsigned)f2bf(a10 * i1) | ((unsigned)f2bf(a11 * i1) << 16);
  *(unsigned*)&Xagg[(size_t)node * 1024 + h0 * 128 + c] = o0;
  *(unsigned*)&Xagg[(size_t)node * 1024 + h1 * 128 + c] = o1;
}

// ---------- z = ELU(Xagg @ WbT^T + b1), bf16 out; M x 1024 x 64 ----------
__global__ __launch_bounds__(256) void gemm_z(
    const unsigned short* __restrict__ Xagg, const unsigned short* __restrict__ WbT,
    const float* __restrict__ b1, unsigned short* __restrict__ zb, int M) {
  int wave = threadIdx.x >> 6, lane = threadIdx.x & 63;
  int q = lane >> 4, t = lane & 15;
  int row0 = blockIdx.x * 64 + wave * 16;
  int arow = row0 + t; if (arow > M - 1) arow = M - 1;
  const bf16x8* aptr = (const bf16x8*)(Xagg + (size_t)arow * 1024);
  const bf16x8* bp0 = (const bf16x8*)(WbT + (size_t)(t) * 1024);
  const bf16x8* bp1 = (const bf16x8*)(WbT + (size_t)(16 + t) * 1024);
  const bf16x8* bp2 = (const bf16x8*)(WbT + (size_t)(32 + t) * 1024);
  const bf16x8* bp3 = (const bf16x8*)(WbT + (size_t)(48 + t) * 1024);
  f32x4 acc[4];
  #pragma unroll
  for (int c = 0; c < 4; c++) acc[c] = (f32x4){0.f, 0.f, 0.f, 0.f};
  #pragma unroll 8
  for (int s = 0; s < 32; s++) {
    bf16x8 a = aptr[s * 4 + q];
    acc[0] = __builtin_amdgcn_mfma_f32_16x16x32_bf16(a, bp0[s * 4 + q], acc[0], 0, 0, 0);
    acc[1] = __builtin_amdgcn_mfma_f32_16x16x32_bf16(a, bp1[s * 4 + q], acc[1], 0, 0, 0);
    acc[2] = __builtin_amdgcn_mfma_f32_16x16x32_bf16(a, bp2[s * 4 + q], acc[2], 0, 0, 0);
    acc[3] = __builtin_amdgcn_mfma_f32_16x16x32_bf16(a, bp3[s * 4 + q], acc[3], 0, 0, 0);
  }
  #pragma unroll
  for (int c = 0; c < 4; c++) {
    int col = c * 16 + t;
    float bias = b1[col];
    #pragma unroll
    for (int r = 0; r < 4; r++) {
      int row = row0 + q * 4 + r;
      float v = acc[c][r] + bias;
      v = (v > 0.f) ? v : (__expf(v) - 1.f);  // ELU
      if (row < M) zb[(size_t)row * 64 + col] = f2bf(v);
    }
  }
}

// ---------- layer-2 aggregation: wave per dst node ----------
__global__ __launch_bounds__(256) void aggregate2(
    const int* __restrict__ offsets, const int* __restrict__ srcs,
    const float* __restrict__ w2buf, const unsigned short* __restrict__ h2,
    const float* __restrict__ b2, float* __restrict__ out, int n) {
  int wid = (int)((blockIdx.x * blockDim.x + threadIdx.x) >> 6);
  int lane = threadIdx.x & 63;
  if (wid >= n) return;
  int beg = offsets[wid], end = offsets[wid + 1];
  float acc = 0.f, accw = 0.f;
  for (int j = beg; j < end; j++) {
    int src = srcs[j];
    float w = w2buf[j];
    accw += w;
    acc += w * bf2f(h2[(size_t)src * 64 + lane]);
  }
  out[(size_t)wid * 64 + lane] = acc / accw + b2[lane];
}

// ---------- host launch ----------
extern "C" void kernel_launch(void* const* d_in, const int* in_sizes, int n_in,
                              void* d_out, int out_size, void* d_ws, size_t ws_size,
                              hipStream_t stream) {
  const int IN = 128;
  const int N = in_sizes[0] / IN;      // 50000
  const int E = in_sizes[1] / 2;       // 400000
  const int ET = E + N;                // with self-loops

  const float* x        = (const float*)d_in[0];
  const int*   ei       = (const int*)d_in[1];
  const float* W1       = (const float*)d_in[2];
  const float* att_src1 = (const float*)d_in[3];
  const float* att_dst1 = (const float*)d_in[4];
  const float* b1       = (const float*)d_in[5];
  const float* W2       = (const float*)d_in[6];
  const float* att_src2 = (const float*)d_in[7];
  const float* att_dst2 = (const float*)d_in[8];
  const float* b2       = (const float*)d_in[9];
  float* out = (float*)d_out;

  char* base = (char*)d_ws;
  size_t off = 0;
  auto alloc = [&](size_t bytes) -> char* {
    char* p = base + off;
    off = (off + bytes + 255) & ~(size_t)255;
    return p;
  };
  unsigned short* xb    = (unsigned short*)alloc((size_t)N * 128 * 2);
  unsigned short* AsAdT = (unsigned short*)alloc((size_t)16 * 128 * 2);
  unsigned short* WbT   = (unsigned short*)alloc((size_t)64 * 1024 * 2);
  unsigned short* W2t   = (unsigned short*)alloc((size_t)64 * 64 * 2);
  unsigned short* Xagg  = (unsigned short*)alloc((size_t)N * 1024 * 2);
  unsigned short* zb    = (unsigned short*)alloc((size_t)N * 64 * 2);
  unsigned short* h2    = (unsigned short*)alloc((size_t)N * 64 * 2);
  float* asd1  = (float*)alloc((size_t)N * 16 * 4);
  float* a_s2  = (float*)alloc((size_t)N * 4);
  float* a_d2  = (float*)alloc((size_t)N * 4);
  float* wbuf  = (float*)alloc((size_t)ET * 8 * 4);
  float* w2buf = (float*)alloc((size_t)ET * 4);
  int* offsets = (int*)alloc((size_t)(N + 1) * 4);
  int* srcs    = (int*)alloc((size_t)ET * 4);
  int* dstof   = (int*)alloc((size_t)ET * 4);
  char* zero_begin = base + off;
  int* counts  = (int*)alloc((size_t)N * 4);
  int* cursor  = (int*)alloc((size_t)N * 4);
  char* zero_end = base + off;

  hipMemsetAsync(zero_begin, 0, (size_t)(zero_end - zero_begin), stream);

  const int TB = 256;
  auto cdiv = [](int a, int b) { return (a + b - 1) / b; };

  // CSR build
  count_dst<<<cdiv(ET, TB), TB, 0, stream>>>(ei, counts, E, ET);
  scan_offsets<<<1, 1024, 0, stream>>>(counts, offsets, N);
  fill_srcs<<<cdiv(ET, TB), TB, 0, stream>>>(ei, offsets, cursor, srcs, dstof, E, ET);

  // precompute / casts
  cast4<<<cdiv(N * 128 / 4, TB), TB, 0, stream>>>(x, xb, N * 128 / 4);
  prep_asad<<<cdiv(16 * 128, TB), TB, 0, stream>>>(W1, att_src1, att_dst1, AsAdT);
  prep_wbig<<<cdiv(64 * 1024, TB), TB, 0, stream>>>(W1, WbT);
  cast_t<<<cdiv(64 * 64, TB), TB, 0, stream>>>(W2, W2t, 64, 64);

  // layer 1 (h1 never materialized)
  dots_mfma<<<cdiv(N, 64), TB, 0, stream>>>(xb, AsAdT, asd1, N);
  weights1<<<cdiv(ET * 8, TB), TB, 0, stream>>>(srcs, dstof, asd1, wbuf, ET);
  aggregate_x<<<N, TB, 0, stream>>>(offsets, srcs, wbuf, xb, Xagg);
  gemm_z<<<cdiv(N, 64), TB, 0, stream>>>(Xagg, WbT, b1, zb, N);

  // layer 2
  {
    dim3 g(cdiv(N, 64), 1);
    gemm_attn<2, 1><<<g, TB, 0, stream>>>(zb, W2t, att_src2, att_dst2,
                                          h2, a_s2, a_d2, N);
  }
  weights2<<<cdiv(ET, TB), TB, 0, stream>>>(srcs, dstof, a_s2, a_d2, w2buf, ET);
  aggregate2<<<cdiv(N, 4), TB, 0, stream>>>(offsets, srcs, w2buf, h2, b2, out, N);
}

// Round 4
// 393.714 us; speedup vs baseline: 1.2127x; 1.2127x over previous
//
#include <hip/hip_runtime.h>
#include <cstdint>
#include <cstddef>

#define NEG_SLOPE 0.2f

typedef short bf16x8 __attribute__((ext_vector_type(8)));
typedef float f32x4 __attribute__((ext_vector_type(4)));

// ---------- bf16 <-> f32 helpers (bit-level, RNE) ----------
__device__ __forceinline__ unsigned short f2bf(float f) {
  unsigned u = __float_as_uint(f);
  u = u + 0x7FFFu + ((u >> 16) & 1u);
  return (unsigned short)(u >> 16);
}
__device__ __forceinline__ float bf2f(unsigned short b) {
  return __uint_as_float((unsigned)b << 16);
}

// ======================================================================
// P1: all independent prep work in one launch, partitioned by blockIdx.
//  [0, B0)           count_dst
//  [B0, B0+B1)       cast4 (x -> xb bf16)
//  [.., +8)          prep_asad
//  [.., +256)        prep_wbig
//  [.., +16)         cast_t W2
// ======================================================================
__global__ __launch_bounds__(256) void prep_all(
    const int* __restrict__ ei, int* __restrict__ counts,
    const float* __restrict__ x, unsigned short* __restrict__ xb,
    const float* __restrict__ W1, const float* __restrict__ att_s1,
    const float* __restrict__ att_d1, unsigned short* __restrict__ AsAdT,
    unsigned short* __restrict__ WbT,
    const float* __restrict__ W2, unsigned short* __restrict__ W2t,
    int E, int ET, int N, int B0, int B1) {
  int b = blockIdx.x, tid = threadIdx.x;
  if (b < B0) {  // count_dst
    int i = b * 256 + tid;
    if (i < ET) {
      int dst = (i < E) ? ei[E + i] : (i - E);
      atomicAdd(&counts[dst], 1);
    }
    return;
  }
  b -= B0;
  if (b < B1) {  // cast4: N*128/4 items
    int i = b * 256 + tid;
    int n4 = N * 32;
    if (i < n4) {
      float4 v = ((const float4*)x)[i];
      ushort4 o;
      o.x = f2bf(v.x); o.y = f2bf(v.y); o.z = f2bf(v.z); o.w = f2bf(v.w);
      ((ushort4*)xb)[i] = o;
    }
    return;
  }
  b -= B1;
  if (b < 8) {  // prep_asad: AsAdT[16][128]
    int i = b * 256 + tid;
    int o = i >> 7, k = i & 127, h = o & 7;
    const float* att = (o < 8) ? att_s1 : att_d1;
    float s = 0.f;
    for (int c = 0; c < 64; c++) s += W1[(size_t)k * 512 + h * 64 + c] * att[h * 64 + c];
    AsAdT[i] = f2bf(s);
    return;
  }
  b -= 8;
  if (b < 256) {  // prep_wbig: WbT[64][1024], WbT[o][h*128+c] = W1[c][h*64+o]
    int i = b * 256 + tid;
    int o = i >> 10, k = i & 1023, h = k >> 7, c = k & 127;
    WbT[i] = f2bf(W1[(size_t)c * 512 + h * 64 + o]);
    return;
  }
  b -= 256;
  {  // cast_t W2: W2t[64][64], W2t[nn][k] = W2[k][nn]
    int i = b * 256 + tid;
    if (i < 64 * 64) {
      int k = i >> 6, nn = i & 63;
      W2t[(size_t)nn * 64 + k] = f2bf(W2[i]);
    }
  }
}

// ---------- single-block scan ----------
__global__ __launch_bounds__(1024) void scan_offsets(
    const int* __restrict__ counts, int* __restrict__ offsets, int n) {
  __shared__ int sums[1024];
  int t = threadIdx.x;
  int chunk = (n + 1023) >> 10;
  int start = t * chunk;
  int end = min(start + chunk, n);
  int s = 0;
  for (int i = start; i < end; i++) s += counts[i];
  sums[t] = s;
  __syncthreads();
  for (int off = 1; off < 1024; off <<= 1) {
    int v = (t >= off) ? sums[t - off] : 0;
    __syncthreads();
    sums[t] += v;
    __syncthreads();
  }
  int run = sums[t] - s;
  for (int i = start; i < end; i++) { offsets[i] = run; run += counts[i]; }
  if (t == 1023) offsets[n] = sums[1023];
}

// ======================================================================
// P3: fill_srcs [0,B0) + dots_mfma [B0, B0+B1)
// ======================================================================
__global__ __launch_bounds__(256) void fill_dots(
    const int* __restrict__ ei, const int* __restrict__ offsets,
    int* __restrict__ cursor, int* __restrict__ srcs, int* __restrict__ dstof,
    const unsigned short* __restrict__ xb, const unsigned short* __restrict__ AsAdT,
    float* __restrict__ asd, int E, int ET, int M, int B0) {
  int b = blockIdx.x, tid = threadIdx.x;
  if (b < B0) {  // fill_srcs
    int i = b * 256 + tid;
    if (i < ET) {
      int src, dst;
      if (i < E) { src = ei[i]; dst = ei[E + i]; } else { src = dst = i - E; }
      int pos = atomicAdd(&cursor[dst], 1);
      int slot = offsets[dst] + pos;
      srcs[slot] = src;
      dstof[slot] = dst;
    }
    return;
  }
  b -= B0;
  // dots_mfma: asd[node][16] = xb @ AsAdT^T
  int wave = tid >> 6, lane = tid & 63;
  int q = lane >> 4, t = lane & 15;
  int row0 = b * 64 + wave * 16;
  int arow = row0 + t; if (arow > M - 1) arow = M - 1;
  const bf16x8* aptr = (const bf16x8*)(xb + (size_t)arow * 128);
  const bf16x8* bptr = (const bf16x8*)(AsAdT + t * 128);
  f32x4 acc = (f32x4){0.f, 0.f, 0.f, 0.f};
  #pragma unroll
  for (int s = 0; s < 4; s++)
    acc = __builtin_amdgcn_mfma_f32_16x16x32_bf16(aptr[s * 4 + q], bptr[s * 4 + q],
                                                  acc, 0, 0, 0);
  #pragma unroll
  for (int r = 0; r < 4; r++) {
    int row = row0 + q * 4 + r;
    if (row < M) asd[row * 16 + t] = acc[r];
  }
}

// ---------- per-(csr-edge, head) softmax numerators, CSR order ----------
__global__ void weights1(const int* __restrict__ srcs, const int* __restrict__ dstof,
                         const float* __restrict__ asd, float* __restrict__ wbuf,
                         int ET) {
  int i = blockIdx.x * blockDim.x + threadIdx.x;
  if (i >= ET * 8) return;
  int j = i >> 3, h = i & 7;
  int src = srcs[j], dst = dstof[j];
  float v = asd[src * 16 + h] + asd[dst * 16 + 8 + h];
  v = (v > 0.f) ? v : NEG_SLOPE * v;
  wbuf[i] = __expf(v);
}

// ======================================================================
// P5: fused layer-1 aggregation + GEMM.  16 nodes/block, 512 threads.
// Edge phase: wave w aggregates nodes {w*2, w*2+1} (8 heads x 128 ch in
// registers: lane holds ch {2l,2l+1} for all 8 heads), normalized rows go
// to LDS bf16 (stride 1032 = 2-way bank aliasing only).
// GEMM phase: waves 0..3 compute z[16][64] = Xtile @ WbT^T + b1, ELU, bf16.
// ======================================================================
__global__ __launch_bounds__(512) void agg1_gemm(
    const int* __restrict__ offsets, const int* __restrict__ srcs,
    const float* __restrict__ wbuf, const unsigned short* __restrict__ xb,
    const unsigned short* __restrict__ WbT, const float* __restrict__ b1,
    unsigned short* __restrict__ zb, int N) {
  __shared__ unsigned short sh[16 * 1032];
  int tid = threadIdx.x;
  int wv = tid >> 6, lane = tid & 63;
  int nb = blockIdx.x;
  #pragma unroll
  for (int i = 0; i < 2; i++) {
    int row = wv * 2 + i;
    int node = nb * 16 + row;
    float2 acc[8];
    float ws[8];
    #pragma unroll
    for (int h = 0; h < 8; h++) { acc[h].x = 0.f; acc[h].y = 0.f; ws[h] = 0.f; }
    int beg = offsets[node], end = offsets[node + 1];
    for (int j = beg; j < end; j++) {
      int src = srcs[j];
      float4 wa = *(const float4*)&wbuf[(size_t)j * 8];
      float4 wb = *(const float4*)&wbuf[(size_t)j * 8 + 4];
      unsigned xv = *(const unsigned*)&xb[(size_t)src * 128 + 2 * lane];
      float x0 = bf2f((unsigned short)(xv & 0xFFFFu));
      float x1 = bf2f((unsigned short)(xv >> 16));
      acc[0].x += wa.x * x0; acc[0].y += wa.x * x1; ws[0] += wa.x;
      acc[1].x += wa.y * x0; acc[1].y += wa.y * x1; ws[1] += wa.y;
      acc[2].x += wa.z * x0; acc[2].y += wa.z * x1; ws[2] += wa.z;
      acc[3].x += wa.w * x0; acc[3].y += wa.w * x1; ws[3] += wa.w;
      acc[4].x += wb.x * x0; acc[4].y += wb.x * x1; ws[4] += wb.x;
      acc[5].x += wb.y * x0; acc[5].y += wb.y * x1; ws[5] += wb.y;
      acc[6].x += wb.z * x0; acc[6].y += wb.z * x1; ws[6] += wb.z;
      acc[7].x += wb.w * x0; acc[7].y += wb.w * x1; ws[7] += wb.w;
    }
    #pragma unroll
    for (int h = 0; h < 8; h++) {
      float iv = 0.125f / ws[h];  // head-mean folded in
      unsigned o = (unsigned)f2bf(acc[h].x * iv) | ((unsigned)f2bf(acc[h].y * iv) << 16);
      *(unsigned*)&sh[row * 1032 + h * 128 + 2 * lane] = o;
    }
  }
  __syncthreads();
  if (wv < 4) {
    int q = lane >> 4, t = lane & 15;
    f32x4 acc4 = (f32x4){0.f, 0.f, 0.f, 0.f};
    const unsigned short* bbase = WbT + (size_t)(wv * 16 + t) * 1024;
    #pragma unroll 8
    for (int s = 0; s < 32; s++) {
      bf16x8 af = *(const bf16x8*)&sh[t * 1032 + s * 32 + q * 8];
      bf16x8 bf = *(const bf16x8*)&bbase[s * 32 + q * 8];
      acc4 = __builtin_amdgcn_mfma_f32_16x16x32_bf16(af, bf, acc4, 0, 0, 0);
    }
    int col = wv * 16 + t;
    float bias = b1[col];
    #pragma unroll
    for (int r = 0; r < 4; r++) {
      int row = q * 4 + r;
      int node = nb * 16 + row;
      float v = acc4[r] + bias;
      v = (v > 0.f) ? v : (__expf(v) - 1.f);  // ELU
      if (node < N) zb[(size_t)node * 64 + col] = f2bf(v);
    }
  }
}

// ---------- layer-2 GEMM + attention dots ----------
template <int KS, int H>
__global__ __launch_bounds__(256) void gemm_attn(
    const unsigned short* __restrict__ Ab, const unsigned short* __restrict__ Wt,
    const float* __restrict__ atts, const float* __restrict__ attd,
    unsigned short* __restrict__ Hout, float* __restrict__ as_out,
    float* __restrict__ ad_out, int M) {
  const int K = KS * 32;
  int wave = threadIdx.x >> 6, lane = threadIdx.x & 63;
  int q = lane >> 4, t = lane & 15;
  int hd = blockIdx.y;
  int row0 = blockIdx.x * 64 + wave * 16;

  int arow = row0 + t; if (arow > M - 1) arow = M - 1;
  const bf16x8* aptr = (const bf16x8*)(Ab + (size_t)arow * K);
  bf16x8 afr[KS];
  #pragma unroll
  for (int s = 0; s < KS; s++) afr[s] = aptr[s * 4 + q];

  f32x4 acc[4];
  #pragma unroll
  for (int c = 0; c < 4; c++) acc[c] = (f32x4){0.f, 0.f, 0.f, 0.f};
  #pragma unroll
  for (int c = 0; c < 4; c++) {
    const bf16x8* bptr = (const bf16x8*)(Wt + (size_t)(hd * 64 + c * 16 + t) * K);
    #pragma unroll
    for (int s = 0; s < KS; s++) {
      acc[c] = __builtin_amdgcn_mfma_f32_16x16x32_bf16(afr[s], bptr[s * 4 + q],
                                                       acc[c], 0, 0, 0);
    }
  }

  float ps[4] = {0, 0, 0, 0}, pd[4] = {0, 0, 0, 0};
  #pragma unroll
  for (int c = 0; c < 4; c++) {
    int col = c * 16 + t;
    float wsc = atts[hd * 64 + col], wdc = attd[hd * 64 + col];
    #pragma unroll
    for (int r = 0; r < 4; r++) {
      float v = acc[c][r];
      int row = row0 + q * 4 + r;
      if (row < M) Hout[(size_t)row * (H * 64) + hd * 64 + col] = f2bf(v);
      ps[r] += v * wsc;
      pd[r] += v * wdc;
    }
  }
  #pragma unroll
  for (int r = 0; r < 4; r++) {
    float s = ps[r], d = pd[r];
    #pragma unroll
    for (int off = 1; off < 16; off <<= 1) {
      s += __shfl_xor(s, off, 64);
      d += __shfl_xor(d, off, 64);
    }
    int row = row0 + q * 4 + r;
    if (t == 0 && row < M) {
      as_out[row * H + hd] = s;
      ad_out[row * H + hd] = d;
    }
  }
}

// ---------- layer-2 aggregation with fused edge weights: wave per dst ----------
__global__ __launch_bounds__(256) void aggregate2(
    const int* __restrict__ offsets, const int* __restrict__ srcs,
    const float* __restrict__ as2, const float* __restrict__ ad2,
    const unsigned short* __restrict__ h2, const float* __restrict__ b2,
    float* __restrict__ out, int n) {
  int wid = (int)((blockIdx.x * blockDim.x + threadIdx.x) >> 6);
  int lane = threadIdx.x & 63;
  if (wid >= n) return;
  float adv = ad2[wid];
  int beg = offsets[wid], end = offsets[wid + 1];
  float acc = 0.f, accw = 0.f;
  for (int j = beg; j < end; j++) {
    int src = srcs[j];
    float v = as2[src] + adv;
    v = (v > 0.f) ? v : NEG_SLOPE * v;
    float w = __expf(v);
    accw += w;
    acc += w * bf2f(h2[(size_t)src * 64 + lane]);
  }
  out[(size_t)wid * 64 + lane] = acc / accw + b2[lane];
}

// ---------- host launch ----------
extern "C" void kernel_launch(void* const* d_in, const int* in_sizes, int n_in,
                              void* d_out, int out_size, void* d_ws, size_t ws_size,
                              hipStream_t stream) {
  const int IN = 128;
  const int N = in_sizes[0] / IN;      // 50000
  const int E = in_sizes[1] / 2;       // 400000
  const int ET = E + N;                // with self-loops

  const float* x        = (const float*)d_in[0];
  const int*   ei       = (const int*)d_in[1];
  const float* W1       = (const float*)d_in[2];
  const float* att_src1 = (const float*)d_in[3];
  const float* att_dst1 = (const float*)d_in[4];
  const float* b1       = (const float*)d_in[5];
  const float* W2       = (const float*)d_in[6];
  const float* att_src2 = (const float*)d_in[7];
  const float* att_dst2 = (const float*)d_in[8];
  const float* b2       = (const float*)d_in[9];
  float* out = (float*)d_out;

  char* base = (char*)d_ws;
  size_t off = 0;
  auto alloc = [&](size_t bytes) -> char* {
    char* p = base + off;
    off = (off + bytes + 255) & ~(size_t)255;
    return p;
  };
  unsigned short* xb    = (unsigned short*)alloc((size_t)N * 128 * 2);
  unsigned short* AsAdT = (unsigned short*)alloc((size_t)16 * 128 * 2);
  unsigned short* WbT   = (unsigned short*)alloc((size_t)64 * 1024 * 2);
  unsigned short* W2t   = (unsigned short*)alloc((size_t)64 * 64 * 2);
  unsigned short* zb    = (unsigned short*)alloc((size_t)N * 64 * 2);
  unsigned short* h2    = (unsigned short*)alloc((size_t)N * 64 * 2);
  float* asd1  = (float*)alloc((size_t)N * 16 * 4);
  float* a_s2  = (float*)alloc((size_t)N * 4);
  float* a_d2  = (float*)alloc((size_t)N * 4);
  float* wbuf  = (float*)alloc((size_t)ET * 8 * 4);
  int* offsets = (int*)alloc((size_t)(N + 1) * 4);
  int* srcs    = (int*)alloc((size_t)ET * 4);
  int* dstof   = (int*)alloc((size_t)ET * 4);
  char* zero_begin = base + off;
  int* counts  = (int*)alloc((size_t)N * 4);
  int* cursor  = (int*)alloc((size_t)N * 4);
  char* zero_end = base + off;

  hipMemsetAsync(zero_begin, 0, (size_t)(zero_end - zero_begin), stream);

  const int TB = 256;
  auto cdiv = [](int a, int b) { return (a + b - 1) / b; };

  // P1: all independent prep
  int B0 = cdiv(ET, TB);        // count_dst
  int B1 = cdiv(N * 32, TB);    // cast4
  prep_all<<<B0 + B1 + 8 + 256 + 16, TB, 0, stream>>>(
      ei, counts, x, xb, W1, att_src1, att_dst1, AsAdT, WbT, W2, W2t,
      E, ET, N, B0, B1);

  // P2: scan
  scan_offsets<<<1, 1024, 0, stream>>>(counts, offsets, N);

  // P3: fill CSR + attention dots
  int F0 = cdiv(ET, TB);
  fill_dots<<<F0 + cdiv(N, 64), TB, 0, stream>>>(
      ei, offsets, cursor, srcs, dstof, xb, AsAdT, asd1, E, ET, N, F0);

  // P4: per-(edge,head) softmax numerators
  weights1<<<cdiv(ET * 8, TB), TB, 0, stream>>>(srcs, dstof, asd1, wbuf, ET);

  // P5: fused aggregation + GEMM -> zb
  agg1_gemm<<<cdiv(N, 16), 512, 0, stream>>>(offsets, srcs, wbuf, xb, WbT, b1, zb, N);

  // P6: layer-2 GEMM + dots
  {
    dim3 g(cdiv(N, 64), 1);
    gemm_attn<2, 1><<<g, TB, 0, stream>>>(zb, W2t, att_src2, att_dst2,
                                          h2, a_s2, a_d2, N);
  }

  // P7: layer-2 aggregation (weights fused)
  aggregate2<<<cdiv(N, 4), TB, 0, stream>>>(offsets, srcs, a_s2, a_d2, h2, b2,
                                            out, N);
}

// Round 5
// 383.782 us; speedup vs baseline: 1.2441x; 1.0259x over previous
//
#include <hip/hip_runtime.h>
#include <cstdint>
#include <cstddef>

#define NEG_SLOPE 0.2f

typedef short bf16x8 __attribute__((ext_vector_type(8)));
typedef float f32x4 __attribute__((ext_vector_type(4)));

__device__ __forceinline__ unsigned short f2bf(float f) {
  unsigned u = __float_as_uint(f);
  u = u + 0x7FFFu + ((u >> 16) & 1u);
  return (unsigned short)(u >> 16);
}
__device__ __forceinline__ float bf2f(unsigned short b) {
  return __uint_as_float((unsigned)b << 16);
}

// ======================================================================
// P1: all independent prep, partitioned by blockIdx.
// ======================================================================
__global__ __launch_bounds__(256) void prep_all(
    const int* __restrict__ ei, int* __restrict__ counts,
    const float* __restrict__ x, unsigned short* __restrict__ xb,
    const float* __restrict__ W1, const float* __restrict__ att_s1,
    const float* __restrict__ att_d1, unsigned short* __restrict__ AsAdT,
    unsigned short* __restrict__ WbT,
    const float* __restrict__ W2, unsigned short* __restrict__ W2t,
    const float* __restrict__ att_s2, const float* __restrict__ att_d2,
    float* __restrict__ AsAd2,
    int E, int ET, int N, int B0, int B1) {
  int b = blockIdx.x, tid = threadIdx.x;
  if (b < B0) {  // count_dst
    int i = b * 256 + tid;
    if (i < ET) {
      int dst = (i < E) ? ei[E + i] : (i - E);
      atomicAdd(&counts[dst], 1);
    }
    return;
  }
  b -= B0;
  if (b < B1) {  // cast x -> xb
    int i = b * 256 + tid;
    if (i < N * 32) {
      float4 v = ((const float4*)x)[i];
      ushort4 o;
      o.x = f2bf(v.x); o.y = f2bf(v.y); o.z = f2bf(v.z); o.w = f2bf(v.w);
      ((ushort4*)xb)[i] = o;
    }
    return;
  }
  b -= B1;
  if (b < 8) {  // AsAdT[16][128]
    int i = b * 256 + tid;
    int o = i >> 7, k = i & 127, h = o & 7;
    const float* att = (o < 8) ? att_s1 : att_d1;
    float s = 0.f;
    for (int c = 0; c < 64; c++) s += W1[(size_t)k * 512 + h * 64 + c] * att[h * 64 + c];
    AsAdT[i] = f2bf(s);
    return;
  }
  b -= 8;
  if (b < 256) {  // WbT[64][1024]: WbT[o][h*128+c] = W1[c][h*64+o]
    int i = b * 256 + tid;
    int o = i >> 10, k = i & 1023, h = k >> 7, c = k & 127;
    WbT[i] = f2bf(W1[(size_t)c * 512 + h * 64 + o]);
    return;
  }
  b -= 256;
  if (b < 16) {  // W2t[64][64]: W2t[nn][k] = W2[k][nn]
    int i = b * 256 + tid;
    if (i < 64 * 64) {
      int k = i >> 6, nn = i & 63;
      W2t[(size_t)nn * 64 + k] = f2bf(W2[i]);
    }
    return;
  }
  // AsAd2[2][64]: AsAd2[o][k] = sum_c W2[k][c]*att2_o[c]
  {
    int i = tid;
    if (i < 128) {
      int o = i >> 6, k = i & 63;
      const float* att = (o == 0) ? att_s2 : att_d2;
      float s = 0.f;
      for (int c = 0; c < 64; c++) s += W2[(size_t)k * 64 + c] * att[c];
      AsAd2[i] = s;
    }
  }
}

// ======================================================================
// P2: block 0 = single-block scan; blocks 1.. = layer-1 attention dots.
// ======================================================================
__global__ __launch_bounds__(1024) void scan_dots(
    const int* __restrict__ counts, int* __restrict__ offsets,
    const unsigned short* __restrict__ xb, const unsigned short* __restrict__ AsAdT,
    float* __restrict__ asd, int n) {
  if (blockIdx.x == 0) {
    __shared__ int sums[1024];
    int t = threadIdx.x;
    int chunk = (n + 1023) >> 10;
    int start = t * chunk;
    int end = min(start + chunk, n);
    int s = 0;
    for (int i = start; i < end; i++) s += counts[i];
    sums[t] = s;
    __syncthreads();
    for (int off = 1; off < 1024; off <<= 1) {
      int v = (t >= off) ? sums[t - off] : 0;
      __syncthreads();
      sums[t] += v;
      __syncthreads();
    }
    int run = sums[t] - s;
    for (int i = start; i < end; i++) { offsets[i] = run; run += counts[i]; }
    if (t == 1023) offsets[n] = sums[1023];
    return;
  }
  // dots: asd[node][16] = xb @ AsAdT^T, 16 waves/block -> 256 rows/block
  int tid = threadIdx.x;
  int wave = tid >> 6, lane = tid & 63;
  int q = lane >> 4, t = lane & 15;
  int row0 = (blockIdx.x - 1) * 256 + wave * 16;
  int arow = row0 + t; if (arow > n - 1) arow = n - 1;
  const bf16x8* aptr = (const bf16x8*)(xb + (size_t)arow * 128);
  const bf16x8* bptr = (const bf16x8*)(AsAdT + t * 128);
  f32x4 acc = (f32x4){0.f, 0.f, 0.f, 0.f};
  #pragma unroll
  for (int s = 0; s < 4; s++)
    acc = __builtin_amdgcn_mfma_f32_16x16x32_bf16(aptr[s * 4 + q], bptr[s * 4 + q],
                                                  acc, 0, 0, 0);
  #pragma unroll
  for (int r = 0; r < 4; r++) {
    int row = row0 + q * 4 + r;
    if (row < n) asd[row * 16 + t] = acc[r];
  }
}

// ======================================================================
// P3: CSR fill + per-(edge,head) softmax numerators fused.
// ======================================================================
__global__ __launch_bounds__(256) void fill_weights(
    const int* __restrict__ ei, const int* __restrict__ offsets,
    int* __restrict__ cursor, int* __restrict__ srcs,
    const float* __restrict__ asd, float* __restrict__ wbuf,
    int E, int ET) {
  int i = blockIdx.x * 256 + threadIdx.x;
  if (i >= ET) return;
  int src, dst;
  if (i < E) { src = ei[i]; dst = ei[E + i]; } else { src = dst = i - E; }
  int pos = atomicAdd(&cursor[dst], 1);
  int slot = offsets[dst] + pos;
  srcs[slot] = src;
  float4 s0 = *(const float4*)&asd[src * 16];
  float4 s1 = *(const float4*)&asd[src * 16 + 4];
  float4 d0 = *(const float4*)&asd[dst * 16 + 8];
  float4 d1 = *(const float4*)&asd[dst * 16 + 12];
  float w[8];
  w[0] = s0.x + d0.x; w[1] = s0.y + d0.y; w[2] = s0.z + d0.z; w[3] = s0.w + d0.w;
  w[4] = s1.x + d1.x; w[5] = s1.y + d1.y; w[6] = s1.z + d1.z; w[7] = s1.w + d1.w;
  #pragma unroll
  for (int h = 0; h < 8; h++) {
    float v = w[h];
    v = (v > 0.f) ? v : NEG_SLOPE * v;
    w[h] = __expf(v);
  }
  float4* wp = (float4*)&wbuf[(size_t)slot * 8];
  wp[0] = make_float4(w[0], w[1], w[2], w[3]);
  wp[1] = make_float4(w[4], w[5], w[6], w[7]);
}

// ======================================================================
// P4: fused layer-1 aggregation + GEMM + layer-2 attention dots.
// 16 nodes/block, 1024 thr = 16 waves; edge phase: wave per node.
// ======================================================================
__global__ __launch_bounds__(1024, 8) void agg1_gemm(
    const int* __restrict__ offsets, const int* __restrict__ srcs,
    const float* __restrict__ wbuf, const unsigned short* __restrict__ xb,
    const unsigned short* __restrict__ WbT, const float* __restrict__ b1,
    const float* __restrict__ AsAd2, unsigned short* __restrict__ zb,
    float* __restrict__ as2, float* __restrict__ ad2, int N) {
  __shared__ unsigned short sh[16 * 1032];
  __shared__ float sas[16], sad[16];
  int tid = threadIdx.x;
  int wv = tid >> 6, lane = tid & 63;
  int nb = blockIdx.x;
  {
    int row = wv;
    int node = nb * 16 + row;
    float2 acc[8];
    float ws[8];
    #pragma unroll
    for (int h = 0; h < 8; h++) { acc[h].x = 0.f; acc[h].y = 0.f; ws[h] = 0.f; }
    int beg = offsets[node], end = offsets[node + 1];
    // software pipeline: 1-deep prefetch of (srcs, wbuf, xb)
    int j0 = beg, jl = end - 1;
    int src_p = srcs[j0 <= jl ? j0 : jl];
    float4 wa_p = *(const float4*)&wbuf[(size_t)(j0 <= jl ? j0 : jl) * 8];
    float4 wb_p = *(const float4*)&wbuf[(size_t)(j0 <= jl ? j0 : jl) * 8 + 4];
    unsigned xv_p = *(const unsigned*)&xb[(size_t)src_p * 128 + 2 * lane];
    for (int j = beg; j < end; j++) {
      float4 wa = wa_p, wb = wb_p;
      unsigned xv = xv_p;
      int jn = (j + 1 <= jl) ? j + 1 : jl;
      int nsrc = srcs[jn];
      wa_p = *(const float4*)&wbuf[(size_t)jn * 8];
      wb_p = *(const float4*)&wbuf[(size_t)jn * 8 + 4];
      xv_p = *(const unsigned*)&xb[(size_t)nsrc * 128 + 2 * lane];
      float x0 = __uint_as_float(xv << 16);
      float x1 = __uint_as_float(xv & 0xFFFF0000u);
      acc[0].x += wa.x * x0; acc[0].y += wa.x * x1; ws[0] += wa.x;
      acc[1].x += wa.y * x0; acc[1].y += wa.y * x1; ws[1] += wa.y;
      acc[2].x += wa.z * x0; acc[2].y += wa.z * x1; ws[2] += wa.z;
      acc[3].x += wa.w * x0; acc[3].y += wa.w * x1; ws[3] += wa.w;
      acc[4].x += wb.x * x0; acc[4].y += wb.x * x1; ws[4] += wb.x;
      acc[5].x += wb.y * x0; acc[5].y += wb.y * x1; ws[5] += wb.y;
      acc[6].x += wb.z * x0; acc[6].y += wb.z * x1; ws[6] += wb.z;
      acc[7].x += wb.w * x0; acc[7].y += wb.w * x1; ws[7] += wb.w;
    }
    #pragma unroll
    for (int h = 0; h < 8; h++) {
      float iv = 0.125f / ws[h];  // head-mean folded in
      unsigned o = (unsigned)f2bf(acc[h].x * iv) | ((unsigned)f2bf(acc[h].y * iv) << 16);
      *(unsigned*)&sh[row * 1032 + h * 128 + 2 * lane] = o;
    }
  }
  if (tid < 16) sas[tid] = 0.f;
  else if (tid < 32) sad[tid - 16] = 0.f;
  __syncthreads();
  if (wv < 4) {
    int q = lane >> 4, t = lane & 15;
    f32x4 acc4 = (f32x4){0.f, 0.f, 0.f, 0.f};
    const unsigned short* bbase = WbT + (size_t)(wv * 16 + t) * 1024;
    #pragma unroll 8
    for (int s = 0; s < 32; s++) {
      bf16x8 af = *(const bf16x8*)&sh[t * 1032 + s * 32 + q * 8];
      bf16x8 bf = *(const bf16x8*)&bbase[s * 32 + q * 8];
      acc4 = __builtin_amdgcn_mfma_f32_16x16x32_bf16(af, bf, acc4, 0, 0, 0);
    }
    int col = wv * 16 + t;
    float bias = b1[col];
    float vs = AsAd2[col], vd = AsAd2[64 + col];
    float zr[4];
    #pragma unroll
    for (int r = 0; r < 4; r++) {
      int row = q * 4 + r;
      int node = nb * 16 + row;
      float v = acc4[r] + bias;
      v = (v > 0.f) ? v : (__expf(v) - 1.f);  // ELU
      zr[r] = v;
      zb[(size_t)node * 64 + col] = f2bf(v);
    }
    // layer-2 attention dot partials: reduce over this wave's 16 cols
    #pragma unroll
    for (int r = 0; r < 4; r++) {
      float s = zr[r] * vs, d = zr[r] * vd;
      #pragma unroll
      for (int off = 1; off < 16; off <<= 1) {
        s += __shfl_xor(s, off, 64);
        d += __shfl_xor(d, off, 64);
      }
      if (t == 0) {
        atomicAdd(&sas[q * 4 + r], s);
        atomicAdd(&sad[q * 4 + r], d);
      }
    }
  }
  __syncthreads();
  if (tid < 16) as2[nb * 16 + tid] = sas[tid];
  else if (tid < 32) ad2[nb * 16 + (tid - 16)] = sad[tid - 16];
}

// ======================================================================
// P5: fused layer-2 aggregation + GEMM(W2) + bias -> out.
// 16 nodes/block, 1024 thr; wave per node; lane = channel (64).
// ======================================================================
__global__ __launch_bounds__(1024, 8) void agg2_gemm(
    const int* __restrict__ offsets, const int* __restrict__ srcs,
    const float* __restrict__ as2, const float* __restrict__ ad2,
    const unsigned short* __restrict__ zb, const unsigned short* __restrict__ W2t,
    const float* __restrict__ b2, float* __restrict__ out, int N) {
  __shared__ unsigned short sh[16 * 72];
  int tid = threadIdx.x;
  int wv = tid >> 6, lane = tid & 63;
  int nb = blockIdx.x;
  {
    int node = nb * 16 + wv;
    float adv = ad2[node];
    int beg = offsets[node], end = offsets[node + 1];
    int jl = end - 1;
    float acc = 0.f, ws = 0.f;
    int src_p = srcs[beg <= jl ? beg : jl];
    float as_p = as2[src_p];
    unsigned short zv_p = zb[(size_t)src_p * 64 + lane];
    for (int j = beg; j < end; j++) {
      float asv = as_p;
      unsigned short zv = zv_p;
      int jn = (j + 1 <= jl) ? j + 1 : jl;
      int nsrc = srcs[jn];
      as_p = as2[nsrc];
      zv_p = zb[(size_t)nsrc * 64 + lane];
      float v = asv + adv;
      v = (v > 0.f) ? v : NEG_SLOPE * v;
      float w = __expf(v);
      ws += w;
      acc += w * bf2f(zv);
    }
    sh[wv * 72 + lane] = f2bf(acc / ws);
  }
  __syncthreads();
  if (wv < 4) {
    int q = lane >> 4, t = lane & 15;
    f32x4 acc4 = (f32x4){0.f, 0.f, 0.f, 0.f};
    const unsigned short* bbase = W2t + (size_t)(wv * 16 + t) * 64;
    #pragma unroll
    for (int s = 0; s < 2; s++) {
      bf16x8 af = *(const bf16x8*)&sh[t * 72 + s * 32 + q * 8];
      bf16x8 bf = *(const bf16x8*)&bbase[s * 32 + q * 8];
      acc4 = __builtin_amdgcn_mfma_f32_16x16x32_bf16(af, bf, acc4, 0, 0, 0);
    }
    int col = wv * 16 + t;
    float bias = b2[col];
    #pragma unroll
    for (int r = 0; r < 4; r++) {
      int node = nb * 16 + q * 4 + r;
      if (node < N) out[(size_t)node * 64 + col] = acc4[r] + bias;
    }
  }
}

// ---------- host launch ----------
extern "C" void kernel_launch(void* const* d_in, const int* in_sizes, int n_in,
                              void* d_out, int out_size, void* d_ws, size_t ws_size,
                              hipStream_t stream) {
  const int IN = 128;
  const int N = in_sizes[0] / IN;      // 50000
  const int E = in_sizes[1] / 2;       // 400000
  const int ET = E + N;

  const float* x        = (const float*)d_in[0];
  const int*   ei       = (const int*)d_in[1];
  const float* W1       = (const float*)d_in[2];
  const float* att_src1 = (const float*)d_in[3];
  const float* att_dst1 = (const float*)d_in[4];
  const float* b1       = (const float*)d_in[5];
  const float* W2       = (const float*)d_in[6];
  const float* att_src2 = (const float*)d_in[7];
  const float* att_dst2 = (const float*)d_in[8];
  const float* b2       = (const float*)d_in[9];
  float* out = (float*)d_out;

  char* base = (char*)d_ws;
  size_t off = 0;
  auto alloc = [&](size_t bytes) -> char* {
    char* p = base + off;
    off = (off + bytes + 255) & ~(size_t)255;
    return p;
  };
  unsigned short* xb    = (unsigned short*)alloc((size_t)N * 128 * 2);
  unsigned short* AsAdT = (unsigned short*)alloc((size_t)16 * 128 * 2);
  unsigned short* WbT   = (unsigned short*)alloc((size_t)64 * 1024 * 2);
  unsigned short* W2t   = (unsigned short*)alloc((size_t)64 * 64 * 2);
  unsigned short* zb    = (unsigned short*)alloc((size_t)N * 64 * 2);
  float* AsAd2 = (float*)alloc((size_t)128 * 4);
  float* asd1  = (float*)alloc((size_t)N * 16 * 4);
  float* a_s2  = (float*)alloc((size_t)N * 4);
  float* a_d2  = (float*)alloc((size_t)N * 4);
  float* wbuf  = (float*)alloc((size_t)ET * 8 * 4);
  int* offsets = (int*)alloc((size_t)(N + 1) * 4);
  int* srcs    = (int*)alloc((size_t)ET * 4);
  char* zero_begin = base + off;
  int* counts  = (int*)alloc((size_t)N * 4);
  int* cursor  = (int*)alloc((size_t)N * 4);
  char* zero_end = base + off;

  hipMemsetAsync(zero_begin, 0, (size_t)(zero_end - zero_begin), stream);

  const int TB = 256;
  auto cdiv = [](int a, int b) { return (a + b - 1) / b; };

  // P1
  int B0 = cdiv(ET, TB);
  int B1 = cdiv(N * 32, TB);
  prep_all<<<B0 + B1 + 8 + 256 + 16 + 1, TB, 0, stream>>>(
      ei, counts, x, xb, W1, att_src1, att_dst1, AsAdT, WbT, W2, W2t,
      att_src2, att_dst2, AsAd2, E, ET, N, B0, B1);

  // P2: scan (block 0) + layer-1 dots (blocks 1..)
  scan_dots<<<1 + cdiv(N, 256), 1024, 0, stream>>>(counts, offsets, xb, AsAdT,
                                                   asd1, N);

  // P3: CSR fill + edge weights
  fill_weights<<<cdiv(ET, TB), TB, 0, stream>>>(ei, offsets, cursor, srcs,
                                                asd1, wbuf, E, ET);

  // P4: aggregation + GEMM + layer-2 dots
  agg1_gemm<<<cdiv(N, 16), 1024, 0, stream>>>(offsets, srcs, wbuf, xb, WbT, b1,
                                              AsAd2, zb, a_s2, a_d2, N);

  // P5: layer-2 aggregation + GEMM -> out
  agg2_gemm<<<cdiv(N, 16), 1024, 0, stream>>>(offsets, srcs, a_s2, a_d2, zb,
                                              W2t, b2, out, N);
}